// Round 7
// baseline (226.963 us; speedup 1.0000x reference)
//
#include <hip/hip_runtime.h>

#define IMG_H 512
#define IMG_W 512
#define RH 16            // output rows per block; 18 input rows read (1.125x halo)
#define NBX (IMG_H / RH) // 32 row-blocks

// Round-7: EXACTLY round 2's kernel body (rotation loop, no LDS/barriers,
// float2+predicated-scalar halo loads, VGPR ~48) with ONE change: RH 32->16.
// Evidence: VALU-issue time is invariant at 45+-3 us across six structures;
// dur = 45us / VALUBusy. 1536 blocks = 6 blocks/CU with no replenishment ->
// ~13 effective waves/CU -> VALUBusy ~50%. 3072 blocks (1.5x wave-slot
// supply, continuous replenishment) should lift VALUBusy/occupancy.
// (r3 was NOT this test: its full unroll pushed VGPR to 112.)
// Per-pixel math bit-identical; RH=16 partial grouping validated absmax=0 in r3.

typedef float v2f __attribute__((ext_vector_type(2), aligned(8)));

__global__ __launch_bounds__(256) void ssim_main_kernel(
    const float* __restrict__ img1, const float* __restrict__ img2,
    double* __restrict__ partial)
{
    // f32-rounded Gaussian(sigma=1.5, k=3) weights, matching JAX's f32 computation
    constexpr float W_E = 0.30780133f;  // exp(-1/4.5)/(1+2exp(-1/4.5))
    constexpr float W_C = 0.38439734f;  // 1/(1+2exp(-1/4.5))
    constexpr float C1c = 1e-4f;
    constexpr float C2c = 9e-4f;

    const int t = threadIdx.x;
    const int y0 = blockIdx.x * RH;
    const size_t base = (size_t)blockIdx.y * (size_t)(IMG_H * IMG_W);
    const float* __restrict__ A = img1 + base;
    const float* __restrict__ B = img2 + base;
    const bool has_l = (t > 0);    // col 2t-1 exists (else zero border)
    const bool has_r = (t < 255);  // col 2t+2 exists (else zero border)
    const int x = 2 * t;

    // rolling window of horizontal conv sums: [2 cols][3 row slots]
    float h1[2][3], h2[2][3], h11[2][3], h22[2][3], h12[2][3];
    float tsum = 0.0f;

    // two register row-buffers (names only; no runtime indexing)
    float a00, a01, a02, a03, b00, b01, b02, b03;  // buf0
    float a10, a11, a12, a13, b10, b11, b12, b13;  // buf1

#define LOADROW(AP, BP, OFF) do {                                   \
    const v2f _ma = *(const v2f*)(A + (OFF));                       \
    const v2f _mb = *(const v2f*)(B + (OFF));                       \
    AP##1 = _ma.x; AP##2 = _ma.y; BP##1 = _mb.x; BP##2 = _mb.y;     \
    AP##0 = has_l ? A[(OFF) - 1] : 0.0f;                            \
    AP##3 = has_r ? A[(OFF) + 2] : 0.0f;                            \
    BP##0 = has_l ? B[(OFF) - 1] : 0.0f;                            \
    BP##3 = has_r ? B[(OFF) + 2] : 0.0f;                            \
} while (0)

#define ZEROROW(AP, BP) do {                                        \
    AP##0 = 0.f; AP##1 = 0.f; AP##2 = 0.f; AP##3 = 0.f;             \
    BP##0 = 0.f; BP##1 = 0.f; BP##2 = 0.f; BP##3 = 0.f;             \
} while (0)

    // horizontal 3-tap pass for row in buffer (AP,BP) into window slot S
#define HPASS(AP, BP, S) do {                                               \
    const float sa0 = AP##0 * AP##0, sa1 = AP##1 * AP##1;                   \
    const float sa2 = AP##2 * AP##2, sa3 = AP##3 * AP##3;                   \
    const float sb0 = BP##0 * BP##0, sb1 = BP##1 * BP##1;                   \
    const float sb2 = BP##2 * BP##2, sb3 = BP##3 * BP##3;                   \
    const float p0 = AP##0 * BP##0, p1 = AP##1 * BP##1;                     \
    const float p2 = AP##2 * BP##2, p3 = AP##3 * BP##3;                     \
    h1[0][S]  = W_E * (AP##0 + AP##2) + W_C * AP##1;                        \
    h1[1][S]  = W_E * (AP##1 + AP##3) + W_C * AP##2;                        \
    h2[0][S]  = W_E * (BP##0 + BP##2) + W_C * BP##1;                        \
    h2[1][S]  = W_E * (BP##1 + BP##3) + W_C * BP##2;                        \
    h11[0][S] = W_E * (sa0 + sa2) + W_C * sa1;                              \
    h11[1][S] = W_E * (sa1 + sa3) + W_C * sa2;                              \
    h22[0][S] = W_E * (sb0 + sb2) + W_C * sb1;                              \
    h22[1][S] = W_E * (sb1 + sb3) + W_C * sb2;                              \
    h12[0][S] = W_E * (p0 + p2) + W_C * p1;                                 \
    h12[1][S] = W_E * (p1 + p3) + W_C * p2;                                 \
} while (0)

    // vertical 3-tap + SSIM; ends = slots E0,E1, middle = MID
#define VOUT(E0, E1, MID) do {                                              \
    _Pragma("unroll")                                                       \
    for (int c = 0; c < 2; ++c) {                                           \
        const float mu1 = W_E * (h1[c][E0] + h1[c][E1]) + W_C * h1[c][MID]; \
        const float mu2 = W_E * (h2[c][E0] + h2[c][E1]) + W_C * h2[c][MID]; \
        const float e11 = W_E * (h11[c][E0] + h11[c][E1]) + W_C * h11[c][MID]; \
        const float e22 = W_E * (h22[c][E0] + h22[c][E1]) + W_C * h22[c][MID]; \
        const float e12 = W_E * (h12[c][E0] + h12[c][E1]) + W_C * h12[c][MID]; \
        const float mu1s = mu1 * mu1, mu2s = mu2 * mu2, m12 = mu1 * mu2;    \
        const float s11 = e11 - mu1s, s22 = e22 - mu2s, s12 = e12 - m12;    \
        const float num = (2.0f * m12 + C1c) * (2.0f * s12 + C2c);          \
        const float den = (mu1s + mu2s + C1c) * (s11 + s22 + C2c);          \
        tsum += num / den;                                                  \
    }                                                                       \
} while (0)

    size_t off = (size_t)y0 * IMG_W + x;  // element offset of row y0, col x

    // i=0: input row y0-1 -> buf0 (zeros above the image; uniform branch)
    if (blockIdx.x != 0) LOADROW(a0, b0, off - IMG_W); else ZEROROW(a0, b0);
    // prefetch i=1: row y0 -> buf1
    LOADROW(a1, b1, off);
    HPASS(a0, b0, 0);
    // i=1: prefetch row y0+1 -> buf0; consume buf1 into slot 1
    LOADROW(a0, b0, off + IMG_W);
    HPASS(a1, b1, 1);
    off += 2 * (size_t)IMG_W;  // next row to load: y0+2

    // middle steps i=2..15 (14 steps): 2 groups of 6 (period lcm(3,2)) + 2.
    // Step i: load row y0+i into buf((i+1)%2); consume buf(i%2) slot (i%3).
    // All loaded rows y0+2..y0+15 are interior (no bounds checks).
#pragma unroll 1
    for (int g = 0; g < 2; ++g) {
        LOADROW(a1, b1, off); off += IMG_W; HPASS(a0, b0, 2); VOUT(2, 0, 1);
        LOADROW(a0, b0, off); off += IMG_W; HPASS(a1, b1, 0); VOUT(0, 1, 2);
        LOADROW(a1, b1, off); off += IMG_W; HPASS(a0, b0, 1); VOUT(1, 2, 0);
        LOADROW(a0, b0, off); off += IMG_W; HPASS(a1, b1, 2); VOUT(2, 0, 1);
        LOADROW(a1, b1, off); off += IMG_W; HPASS(a0, b0, 0); VOUT(0, 1, 2);
        LOADROW(a0, b0, off); off += IMG_W; HPASS(a1, b1, 1); VOUT(1, 2, 0);
    }
    // i=14: load y0+14 -> buf1; consume buf0 slot 2
    LOADROW(a1, b1, off); off += IMG_W; HPASS(a0, b0, 2); VOUT(2, 0, 1);
    // i=15: load y0+15 -> buf0; consume buf1 slot 0
    LOADROW(a0, b0, off); off += IMG_W; HPASS(a1, b1, 0); VOUT(0, 1, 2);

    // i=16: consume buf0 slot 1; prefetch last input row y0+16 (zeros below
    // the image for the last block; interior otherwise)
    if (blockIdx.x != NBX - 1) LOADROW(a1, b1, off); else ZEROROW(a1, b1);
    HPASS(a0, b0, 1); VOUT(1, 2, 0);
    // i=17: consume buf1 slot 2
    HPASS(a1, b1, 2); VOUT(2, 0, 1);

#undef LOADROW
#undef ZEROROW
#undef HPASS
#undef VOUT

    // 64-lane wave reduction (f32, same order as before)
#pragma unroll
    for (int o = 32; o >= 1; o >>= 1)
        tsum += __shfl_xor(tsum, o, 64);

    __shared__ float wpart[4];
    if ((t & 63) == 0) wpart[t >> 6] = tsum;
    __syncthreads();
    if (t == 0) {
        partial[(size_t)blockIdx.y * gridDim.x + blockIdx.x] =
            (double)wpart[0] + (double)wpart[1] +
            (double)wpart[2] + (double)wpart[3];
    }
}

// Reduce 3072 per-block double partials -> out = 1 - sum. One block.
__global__ __launch_bounds__(256) void ssim_fin_kernel(
    const double* __restrict__ partial, float* __restrict__ out, int n)
{
    const int t = threadIdx.x;
    double s = 0.0;
    for (int i = t; i < n; i += 256) s += partial[i];
#pragma unroll
    for (int o = 32; o >= 1; o >>= 1)
        s += __shfl_xor(s, o, 64);
    __shared__ double w[4];
    if ((t & 63) == 0) w[t >> 6] = s;
    __syncthreads();
    if (t == 0)
        out[0] = 1.0f - (float)(w[0] + w[1] + w[2] + w[3]);
}

extern "C" void kernel_launch(void* const* d_in, const int* in_sizes, int n_in,
                              void* d_out, int out_size, void* d_ws, size_t ws_size,
                              hipStream_t stream) {
    const float* img1 = (const float*)d_in[0];
    const float* img2 = (const float*)d_in[1];
    float* out = (float*)d_out;
    double* partial = (double*)d_ws;  // needs 32*96*8 = 24576 B of workspace

    const int planes = in_sizes[0] / (IMG_H * IMG_W);  // 32*3 = 96

    dim3 grid(NBX, planes);
    ssim_main_kernel<<<grid, 256, 0, stream>>>(img1, img2, partial);
    ssim_fin_kernel<<<1, 256, 0, stream>>>(partial, out, NBX * planes);
}

// Round 8
// 225.234 us; speedup vs baseline: 1.0077x; 1.0077x over previous
//
#include <hip/hip_runtime.h>

#define IMG_H 512
#define IMG_W 512
#define RH 32   // output rows per block; 34 input rows read (1.0625x halo overfetch)

// Round-8: r2 structure VERBATIM (best: 89.4 us; rotation loop, RH=32, no
// LDS/barriers, float2+predicated-scalar halos, all 1536 blocks resident)
// with the math re-factored to cut VALU instructions ~21%:
//  1. ess-fold: SSIM uses only e11+e22 -> one conv of ss=a^2+b^2 (fma) instead
//     of separate conv(a^2), conv(b^2).  (4 channels instead of 5)
//  2. unscaled separable weights: w = W_E*[1,RW,1], RW=W_C/W_E ->
//     H' = (l+r)+RW*m (2 ops vs 3); scale K2=W_E^2 applied once per vertical.
// Theory being tested: VALU-pipe saturation (dur*VALUBusy invariant 45 us
// across 6 structures; occupancy sweeps 29-49% never moved dur; dur tracked
// +5.9% work in r7). If right: dur ~ -20%. If dur unchanged: theory dead.
// NOTE: per-pixel rounding changes by ~1-2 ulp vs the bit-exact versions
// (accepted risk; revert to r2 body if verification fails).

typedef float v2f __attribute__((ext_vector_type(2), aligned(8)));

__global__ __launch_bounds__(256) void ssim_main_kernel(
    const float* __restrict__ img1, const float* __restrict__ img2,
    double* __restrict__ partial)
{
    // f32-rounded Gaussian(sigma=1.5, k=3) weights, matching JAX's f32 computation
    constexpr float W_E = 0.30780133f;  // exp(-1/4.5)/(1+2exp(-1/4.5))
    constexpr float W_C = 0.38439734f;  // 1/(1+2exp(-1/4.5))
    constexpr float RW = W_C / W_E;     // center/edge ratio (constexpr f32)
    constexpr float K2 = W_E * W_E;     // separable scale, applied per vertical
    constexpr float C1c = 1e-4f;
    constexpr float C2c = 9e-4f;

    const int t = threadIdx.x;
    const int y0 = blockIdx.x * RH;
    const size_t base = (size_t)blockIdx.y * (size_t)(IMG_H * IMG_W);
    const float* __restrict__ A = img1 + base;
    const float* __restrict__ B = img2 + base;
    const bool has_l = (t > 0);    // col 2t-1 exists (else zero border)
    const bool has_r = (t < 255);  // col 2t+2 exists (else zero border)
    const int x = 2 * t;

    // rolling window of UNSCALED horizontal conv sums: [2 cols][3 row slots]
    // channels: n1=a, n2=b, nss=a^2+b^2, n12=a*b
    float n1[2][3], n2[2][3], nss[2][3], n12[2][3];
    float tsum = 0.0f;

    // two register row-buffers (names only; no runtime indexing)
    float a00, a01, a02, a03, b00, b01, b02, b03;  // buf0
    float a10, a11, a12, a13, b10, b11, b12, b13;  // buf1

#define LOADROW(AP, BP, OFF) do {                                   \
    const v2f _ma = *(const v2f*)(A + (OFF));                       \
    const v2f _mb = *(const v2f*)(B + (OFF));                       \
    AP##1 = _ma.x; AP##2 = _ma.y; BP##1 = _mb.x; BP##2 = _mb.y;     \
    AP##0 = has_l ? A[(OFF) - 1] : 0.0f;                            \
    AP##3 = has_r ? A[(OFF) + 2] : 0.0f;                            \
    BP##0 = has_l ? B[(OFF) - 1] : 0.0f;                            \
    BP##3 = has_r ? B[(OFF) + 2] : 0.0f;                            \
} while (0)

#define ZEROROW(AP, BP) do {                                        \
    AP##0 = 0.f; AP##1 = 0.f; AP##2 = 0.f; AP##3 = 0.f;             \
    BP##0 = 0.f; BP##1 = 0.f; BP##2 = 0.f; BP##3 = 0.f;             \
} while (0)

    // horizontal unscaled 3-tap [1,RW,1] into window slot S
#define HPASS(AP, BP, S) do {                                               \
    const float ss0 = __builtin_fmaf(BP##0, BP##0, AP##0 * AP##0);          \
    const float ss1 = __builtin_fmaf(BP##1, BP##1, AP##1 * AP##1);          \
    const float ss2 = __builtin_fmaf(BP##2, BP##2, AP##2 * AP##2);          \
    const float ss3 = __builtin_fmaf(BP##3, BP##3, AP##3 * AP##3);          \
    const float p0 = AP##0 * BP##0, p1 = AP##1 * BP##1;                     \
    const float p2 = AP##2 * BP##2, p3 = AP##3 * BP##3;                     \
    n1[0][S]  = __builtin_fmaf(RW, AP##1, AP##0 + AP##2);                   \
    n1[1][S]  = __builtin_fmaf(RW, AP##2, AP##1 + AP##3);                   \
    n2[0][S]  = __builtin_fmaf(RW, BP##1, BP##0 + BP##2);                   \
    n2[1][S]  = __builtin_fmaf(RW, BP##2, BP##1 + BP##3);                   \
    nss[0][S] = __builtin_fmaf(RW, ss1, ss0 + ss2);                         \
    nss[1][S] = __builtin_fmaf(RW, ss2, ss1 + ss3);                         \
    n12[0][S] = __builtin_fmaf(RW, p1, p0 + p2);                            \
    n12[1][S] = __builtin_fmaf(RW, p2, p1 + p3);                            \
} while (0)

    // vertical unscaled 3-tap + K2 scale + SSIM; ends E0,E1, middle MID
#define VOUT(E0, E1, MID) do {                                              \
    _Pragma("unroll")                                                       \
    for (int c = 0; c < 2; ++c) {                                           \
        const float mu1 = K2 * __builtin_fmaf(RW, n1[c][MID],  n1[c][E0] + n1[c][E1]);  \
        const float mu2 = K2 * __builtin_fmaf(RW, n2[c][MID],  n2[c][E0] + n2[c][E1]);  \
        const float ess = K2 * __builtin_fmaf(RW, nss[c][MID], nss[c][E0] + nss[c][E1]);\
        const float e12 = K2 * __builtin_fmaf(RW, n12[c][MID], n12[c][E0] + n12[c][E1]);\
        const float mu1s = mu1 * mu1, mu2s = mu2 * mu2, m12 = mu1 * mu2;    \
        const float sss = (ess - mu1s) - mu2s;                              \
        const float s12 = e12 - m12;                                        \
        const float num = __builtin_fmaf(2.0f, m12, C1c) *                  \
                          __builtin_fmaf(2.0f, s12, C2c);                   \
        const float den = ((mu1s + mu2s) + C1c) * (sss + C2c);              \
        tsum += num / den;                                                  \
    }                                                                       \
} while (0)

    size_t off = (size_t)y0 * IMG_W + x;  // element offset of row y0, col x

    // i=0: input row y0-1 -> buf0 (zeros above the image; uniform branch)
    if (blockIdx.x != 0) LOADROW(a0, b0, off - IMG_W); else ZEROROW(a0, b0);
    // prefetch i=1: row y0 -> buf1
    LOADROW(a1, b1, off);
    HPASS(a0, b0, 0);
    // i=1: prefetch row y0+1 -> buf0; consume buf1 into slot 1
    LOADROW(a0, b0, off + IMG_W);
    HPASS(a1, b1, 1);
    off += 2 * (size_t)IMG_W;  // next row to load: y0+2

    // middle steps i=2..31 (rows y0+1..y0+30 consumed; rows y0+2..y0+31
    // prefetched — all interior). 30 steps = 5 groups of 6 (period lcm(3,2));
    // pattern per step i: consume buf(i%2) slot (i%3).
#pragma unroll 1
    for (int g = 0; g < 5; ++g) {
        LOADROW(a1, b1, off); off += IMG_W; HPASS(a0, b0, 2); VOUT(2, 0, 1);
        LOADROW(a0, b0, off); off += IMG_W; HPASS(a1, b1, 0); VOUT(0, 1, 2);
        LOADROW(a1, b1, off); off += IMG_W; HPASS(a0, b0, 1); VOUT(1, 2, 0);
        LOADROW(a0, b0, off); off += IMG_W; HPASS(a1, b1, 2); VOUT(2, 0, 1);
        LOADROW(a1, b1, off); off += IMG_W; HPASS(a0, b0, 0); VOUT(0, 1, 2);
        LOADROW(a0, b0, off); off += IMG_W; HPASS(a1, b1, 1); VOUT(1, 2, 0);
    }

    // i=32: consume buf0 slot 2; prefetch last input row y0+32 (zeros below image)
    if (blockIdx.x != (IMG_H / RH - 1)) LOADROW(a1, b1, off); else ZEROROW(a1, b1);
    HPASS(a0, b0, 2); VOUT(2, 0, 1);
    // i=33: consume buf1 slot 0
    HPASS(a1, b1, 0); VOUT(0, 1, 2);

#undef LOADROW
#undef ZEROROW
#undef HPASS
#undef VOUT

    // 64-lane wave reduction (f32, same order as before)
#pragma unroll
    for (int o = 32; o >= 1; o >>= 1)
        tsum += __shfl_xor(tsum, o, 64);

    __shared__ float wpart[4];
    if ((t & 63) == 0) wpart[t >> 6] = tsum;
    __syncthreads();
    if (t == 0) {
        partial[(size_t)blockIdx.y * gridDim.x + blockIdx.x] =
            (double)wpart[0] + (double)wpart[1] +
            (double)wpart[2] + (double)wpart[3];
    }
}

// Reduce 1536 per-block double partials -> out = 1 - sum. One block.
__global__ __launch_bounds__(256) void ssim_fin_kernel(
    const double* __restrict__ partial, float* __restrict__ out, int n)
{
    const int t = threadIdx.x;
    double s = 0.0;
    for (int i = t; i < n; i += 256) s += partial[i];
#pragma unroll
    for (int o = 32; o >= 1; o >>= 1)
        s += __shfl_xor(s, o, 64);
    __shared__ double w[4];
    if ((t & 63) == 0) w[t >> 6] = s;
    __syncthreads();
    if (t == 0)
        out[0] = 1.0f - (float)(w[0] + w[1] + w[2] + w[3]);
}

extern "C" void kernel_launch(void* const* d_in, const int* in_sizes, int n_in,
                              void* d_out, int out_size, void* d_ws, size_t ws_size,
                              hipStream_t stream) {
    const float* img1 = (const float*)d_in[0];
    const float* img2 = (const float*)d_in[1];
    float* out = (float*)d_out;
    double* partial = (double*)d_ws;  // needs 16*96*8 = 12288 B of workspace

    const int planes = in_sizes[0] / (IMG_H * IMG_W);  // 32*3 = 96
    const int nblk = IMG_H / RH;                        // 16

    dim3 grid(nblk, planes);
    ssim_main_kernel<<<grid, 256, 0, stream>>>(img1, img2, partial);
    ssim_fin_kernel<<<1, 256, 0, stream>>>(partial, out, nblk * planes);
}